// Round 14
// baseline (465.862 us; speedup 1.0000x reference)
//
#include <hip/hip_runtime.h>
#include <hip/hip_bf16.h>
#include <cstdio>
#include <cstdint>

#define B_    2
#define S_    2048
#define H_    32
#define KVH_  8
#define D_    128
#define HID_  4096
#define WIN_  512
#define NROW_ (B_*S_)          // 4096 rows for projection GEMMs
#define NKV_  2048             // fused k|v output width
#define SCALE_ 0.08838834764831845f          // 128^-0.5
#define SL2E_  0.12751744932973953f          // SCALE_ * log2(e)

typedef __attribute__((ext_vector_type(8))) __bf16 bf16x8;
typedef __attribute__((ext_vector_type(4))) __bf16 bf16x4;
typedef __attribute__((ext_vector_type(4))) float  f32x4;

#define GAS __attribute__((address_space(1)))
#define LAS __attribute__((address_space(3)))

// ------------------------------------------------- merged prep: cvt hidden + 4 weight transposes
__global__ __launch_bounds__(256) void prep_all(const float* __restrict__ hidden,
                                                const float* __restrict__ wq,
                                                const float* __restrict__ wk,
                                                const float* __restrict__ wv,
                                                const float* __restrict__ wo,
                                                __hip_bfloat16* __restrict__ hb,
                                                __hip_bfloat16* __restrict__ wqT,
                                                __hip_bfloat16* __restrict__ wkvT,
                                                __hip_bfloat16* __restrict__ woT) {
    __shared__ float t[32][33];
    const int bid = blockIdx.x;
    if (bid < 16384) {
        const int i = (bid * 256 + threadIdx.x) * 4;
        float4 v = *(const float4*)(hidden + i);
        __hip_bfloat162 a, b;
        a.x = __float2bfloat16(v.x); a.y = __float2bfloat16(v.y);
        b.x = __float2bfloat16(v.z); b.y = __float2bfloat16(v.w);
        *(__hip_bfloat162*)(hb + i)     = a;
        *(__hip_bfloat162*)(hb + i + 2) = b;
        return;
    }
    const int tx = threadIdx.x & 31, ty = threadIdx.x >> 5;
    const int id = bid - 16384;
    const float* src; __hip_bfloat16* dst; int C, idx;   // R always 4096
    if (id < 16384)      { src = wq; dst = wqT;  C = 4096; idx = id; }
    else if (id < 20480) { src = wk; dst = wkvT; C = 1024; idx = id - 16384; }
    else if (id < 24576) { src = wv; dst = wkvT + (size_t)1024*HID_; C = 1024; idx = id - 20480; }
    else                 { src = wo; dst = woT;  C = 4096; idx = id - 24576; }
    const int ctiles = C >> 5;
    const int c0 = (idx % ctiles) * 32, r0 = (idx / ctiles) * 32;
    #pragma unroll
    for (int i = 0; i < 4; ++i)
        t[ty + 8*i][tx] = src[(size_t)(r0 + ty + 8*i) * C + c0 + tx];
    __syncthreads();
    #pragma unroll
    for (int i = 0; i < 4; ++i)
        dst[(size_t)(c0 + ty + 8*i) * HID_ + r0 + tx] = __float2bfloat16(t[tx][ty + 8*i]);
}

// ------------------------------------------------- GEMM 256xBN, BK=32, ring-4, 1-barrier/tile
// R10-proven schedule (best measured: MfmaUtil ~49%).  OMODE 0: f32 out.  1: bf16 out.
// 2: KV fused — bx<8: K head-slab [256 s][128 d] gets LayerNorm+RoPE IN-EPILOGUE (each
// block owns the full reduction axis) and writes kr (B,KVH,S,D) directly; bx>=8: V cols
// transposed via LDS into C2 = vt (B,KVH,D,S).
template <int FN, int OMODE>
__global__ __launch_bounds__(512, 2) void gemm_t(const __hip_bfloat16* __restrict__ A,
                                                 const __hip_bfloat16* __restrict__ Bt,
                                                 void* __restrict__ Cv, void* __restrict__ C2,
                                                 const float* __restrict__ knw,
                                                 const float* __restrict__ cosT,
                                                 const float* __restrict__ sinT,
                                                 const int* __restrict__ pids,
                                                 int M, int N, int K, int nbx) {
    constexpr int BN   = FN * 64;
    constexpr int BLD  = BN / 128;                      // B stage loads/thread/tile (2 or 1)
    constexpr int SLOT = (256 + BN) * 32;               // elems per ring slot (A then B)
    __shared__ __align__(16) __hip_bfloat16 L[4 * SLOT];
    const int tid  = threadIdx.x;
    const int lane = tid & 63, w = tid >> 6;
    const int wm = w >> 2, wn = w & 3;                  // 2 x 4 wave grid
    const int lc = lane & 15, lg = lane >> 4;
    const int nwg = gridDim.x, cpx = nwg >> 3;
    const int bid = blockIdx.x;
    const int swz = (bid & 7) * cpx + (bid >> 3);
    const int by = swz / nbx, bx = swz - by * nbx;
    const size_t row0 = (size_t)by * 256, col0 = (size_t)bx * BN;
    const int nt = K >> 5;                              // BK = 32

    const int srow = tid >> 2;
    const int spc  = tid & 3;
    const int slx  = spc ^ ((srow >> 1) & 3);
    const __hip_bfloat16* Ab = A  + row0 * K;
    const __hip_bfloat16* Bb = Bt + col0 * K;

#define STGA(tile_) do {                                                                   \
    const int ss_ = (tile_) & 3;                                                           \
    const int kt_ = ((tile_) < nt) ? (tile_) : (nt - 1);                                   \
    _Pragma("unroll")                                                                      \
    for (int rh_ = 0; rh_ < 2; ++rh_)                                                      \
        __builtin_amdgcn_global_load_lds(                                                  \
            (const GAS void*)(Ab + (size_t)(rh_*128 + srow) * K + kt_*32 + slx*8),         \
            (LAS void*)&L[ss_*SLOT + rh_*4096 + w*512], 16, 0, 0);                         \
} while (0)

#define STGB(tile_) do {                                                                   \
    const int ss_ = (tile_) & 3;                                                           \
    const int kt_ = ((tile_) < nt) ? (tile_) : (nt - 1);                                   \
    _Pragma("unroll")                                                                      \
    for (int bh_ = 0; bh_ < BLD; ++bh_)                                                    \
        __builtin_amdgcn_global_load_lds(                                                  \
            (const GAS void*)(Bb + (size_t)(bh_*128 + srow) * K + kt_*32 + slx*8),         \
            (LAS void*)&L[ss_*SLOT + 8192 + bh_*4096 + w*512], 16, 0, 0);                  \
} while (0)

#define VMW2L() do {                                                                       \
    if constexpr (FN == 4) asm volatile("s_waitcnt vmcnt(8)" ::: "memory");                \
    else                   asm volatile("s_waitcnt vmcnt(6)" ::: "memory");                \
} while (0)

    f32x4 acc[2][4][FN] = {};
    bf16x8 afr0[4], afr1[4], bfr[FN];

    STGA(0); STGB(0); STGA(1); STGB(1); STGA(2); STGB(2);
    VMW2L();
    asm volatile("s_barrier" ::: "memory");

    for (int t = 0; t < nt; ++t) {
        const int s_ = t & 3;
        #pragma unroll
        for (int fn = 0; fn < FN; ++fn) {
            const int rB = wn*(FN*16) + fn*16 + lc;
            bfr[fn] = *(const bf16x8*)&L[s_*SLOT + 8192 + rB*32 + ((lg ^ ((rB >> 1) & 3)) * 8)];
        }
        #pragma unroll
        for (int fm = 0; fm < 4; ++fm) {
            const int rA = wm*128 + fm*16 + lc;
            afr0[fm] = *(const bf16x8*)&L[s_*SLOT + rA*32 + ((lg ^ ((rA >> 1) & 3)) * 8)];
        }
        __builtin_amdgcn_sched_barrier(0);
        #pragma unroll
        for (int fm = 0; fm < 4; ++fm) {
            const int rA = wm*128 + 64 + fm*16 + lc;
            afr1[fm] = *(const bf16x8*)&L[s_*SLOT + rA*32 + ((lg ^ ((rA >> 1) & 3)) * 8)];
        }
        STGA(t + 3);
        asm volatile("s_waitcnt lgkmcnt(4)" ::: "memory");
        __builtin_amdgcn_sched_barrier(0);
        __builtin_amdgcn_s_setprio(1);
        #pragma unroll
        for (int fm = 0; fm < 4; ++fm)
            #pragma unroll
            for (int fn = 0; fn < FN; ++fn)
                acc[0][fm][fn] = __builtin_amdgcn_mfma_f32_16x16x32_bf16(
                    afr0[fm], bfr[fn], acc[0][fm][fn], 0, 0, 0);
        __builtin_amdgcn_s_setprio(0);

        STGB(t + 3);
        asm volatile("s_waitcnt lgkmcnt(0)" ::: "memory");
        __builtin_amdgcn_sched_barrier(0);
        __builtin_amdgcn_s_setprio(1);
        #pragma unroll
        for (int fm = 0; fm < 4; ++fm)
            #pragma unroll
            for (int fn = 0; fn < FN; ++fn)
                acc[1][fm][fn] = __builtin_amdgcn_mfma_f32_16x16x32_bf16(
                    afr1[fm], bfr[fn], acc[1][fm][fn], 0, 0, 0);
        __builtin_amdgcn_s_setprio(0);
        VMW2L();
        asm volatile("s_barrier" ::: "memory");
    }
#undef STGA
#undef STGB
#undef VMW2L
    asm volatile("s_waitcnt vmcnt(0)" ::: "memory");

    if constexpr (OMODE == 0) {
        float* C = (float*)Cv;
        #pragma unroll
        for (int qm = 0; qm < 2; ++qm)
            #pragma unroll
            for (int fm = 0; fm < 4; ++fm)
                #pragma unroll
                for (int fn = 0; fn < FN; ++fn) {
                    const size_t col = col0 + wn*(FN*16) + fn*16 + lc;
                    #pragma unroll
                    for (int rr = 0; rr < 4; ++rr) {
                        const size_t row = row0 + wm*128 + qm*64 + fm*16 + lg*4 + rr;
                        C[row * N + col] = acc[qm][fm][fn][rr];
                    }
                }
    } else if constexpr (OMODE == 1) {
        __hip_bfloat16* C = (__hip_bfloat16*)Cv;
        #pragma unroll
        for (int qm = 0; qm < 2; ++qm)
            #pragma unroll
            for (int fm = 0; fm < 4; ++fm)
                #pragma unroll
                for (int fn = 0; fn < FN; ++fn) {
                    const size_t col = col0 + wn*(FN*16) + fn*16 + lc;
                    #pragma unroll
                    for (int rr = 0; rr < 4; ++rr) {
                        const size_t row = row0 + wm*128 + qm*64 + fm*16 + lg*4 + rr;
                        C[row * N + col] = __float2bfloat16(acc[qm][fm][fn][rr]);
                    }
                }
    } else {                                            // OMODE 2: KV fused (FN==2, BN=128)
        const int bb = (int)(row0 >> 11), s0 = (int)(row0 & 2047);
        if (bx < 8) {
            // ---- K head-slab: acc -> LDS [256][132] bf16, then per-row LN+RoPE -> kr
            const int g = bx;                           // K head index
            __hip_bfloat16* lt = (__hip_bfloat16*)L;    // [256][132] bf16 = 67.6 KB (fits 98KB)
            __syncthreads();                            // all ring reads retired before reuse
            #pragma unroll
            for (int qm = 0; qm < 2; ++qm)
                #pragma unroll
                for (int fm = 0; fm < 4; ++fm)
                    #pragma unroll
                    for (int fn = 0; fn < FN; ++fn) {
                        const int cl = wn*32 + fn*16 + lc;
                        #pragma unroll
                        for (int rr = 0; rr < 4; ++rr) {
                            const int rl = wm*128 + qm*64 + fm*16 + lg*4 + rr;
                            lt[rl*132 + cl] = __float2bfloat16(acc[qm][fm][fn][rr]);
                        }
                    }
            __syncthreads();
            if (tid < 256) {
                const int s = s0 + tid;
                const __hip_bfloat16* rowp = &lt[tid*132];
                // pass 1: mean & var (b64 reads, stride 264B -> ~2-way conflicts, free)
                float sum = 0.f, ssq = 0.f;
                #pragma unroll
                for (int j = 0; j < 32; ++j) {
                    union { bf16x4 v; __hip_bfloat16 e[4]; } u;
                    u.v = *(const bf16x4*)(rowp + j*4);
                    #pragma unroll
                    for (int e = 0; e < 4; ++e) {
                        const float x = __bfloat162float(u.e[e]);
                        sum += x; ssq += x * x;
                    }
                }
                const float mu = sum * (1.f / D_);
                const float rs = rsqrtf(fmaxf(ssq * (1.f / D_) - mu*mu, 0.f) + 1e-5f);
                const int p = pids[bb*S_ + s];
                __hip_bfloat16* ko = (__hip_bfloat16*)Cv + (((size_t)bb*KVH_ + g)*S_ + s) * D_;
                // pass 2: normalize + RoPE (pairs within each 4-group), store 16B chunks
                #pragma unroll
                for (int j = 0; j < 16; ++j) {
                    union { bf16x8 v; __hip_bfloat16 e[8]; } u, o;
                    u.v = *(const bf16x8*)(rowp + j*8);
                    const int d0 = j*8;
                    float wl[8], cc[8], ss2[8], y[8];
                    *(float4*)&wl[0] = *(const float4*)(knw + d0);
                    *(float4*)&wl[4] = *(const float4*)(knw + d0 + 4);
                    *(float4*)&cc[0] = *(const float4*)(cosT + (size_t)p*D_ + d0);
                    *(float4*)&cc[4] = *(const float4*)(cosT + (size_t)p*D_ + d0 + 4);
                    *(float4*)&ss2[0] = *(const float4*)(sinT + (size_t)p*D_ + d0);
                    *(float4*)&ss2[4] = *(const float4*)(sinT + (size_t)p*D_ + d0 + 4);
                    #pragma unroll
                    for (int e = 0; e < 8; ++e)
                        y[e] = wl[e] * (__bfloat162float(u.e[e]) - mu) * rs;
                    #pragma unroll
                    for (int mp = 0; mp < 4; ++mp) {
                        o.e[2*mp]   = __float2bfloat16(y[2*mp]   * cc[2*mp]   - y[2*mp+1] * ss2[2*mp]);
                        o.e[2*mp+1] = __float2bfloat16(y[2*mp+1] * cc[2*mp+1] + y[2*mp]   * ss2[2*mp+1]);
                    }
                    *(bf16x8*)(ko + d0) = o.v;
                }
            }
        } else {                                        // V columns -> vt (B,KVH,D,S) via LDS
            __hip_bfloat16* lt = (__hip_bfloat16*)L;    // [128 d][264 pad]
            __syncthreads();
            #pragma unroll
            for (int qm = 0; qm < 2; ++qm)
                #pragma unroll
                for (int fm = 0; fm < 4; ++fm)
                    #pragma unroll
                    for (int fn = 0; fn < FN; ++fn) {
                        const int cl = wn*32 + fn*16 + lc;
                        #pragma unroll
                        for (int rr = 0; rr < 4; ++rr) {
                            const int rl = wm*128 + qm*64 + fm*16 + lg*4 + rr;
                            lt[cl*264 + rl] = __float2bfloat16(acc[qm][fm][fn][rr]);
                        }
                    }
            __syncthreads();
            const int g = (int)((col0 - 1024) >> 7);
            __hip_bfloat16* vto = (__hip_bfloat16*)C2 + (((size_t)bb*KVH_ + g) * D_) * (size_t)S_;
            const int d = tid >> 2, sc0 = (tid & 3) * 64;
            #pragma unroll
            for (int j = 0; j < 64; j += 8) {
                bf16x8 v = *(const bf16x8*)&lt[d*264 + sc0 + j];
                *(bf16x8*)&vto[(size_t)d*S_ + s0 + sc0 + j] = v;
            }
        }
    }
}

// chunk swizzle for attn K tile (16B chunks, 16/row)
static __device__ __forceinline__ int sigk_(int r) { return (r & 3) | ((r >> 1) & 4); }

// ------------------------------------------------- sliding-window GQA flash attention v4
// (unchanged from R10 — 8 waves / 128 q-rows, fused Q LN+RoPE, counted vmcnt staging)
__global__ __launch_bounds__(512, 4) void attn_fwd(const __hip_bfloat16* __restrict__ qfb,
                                                   const __hip_bfloat16* __restrict__ kr,
                                                   const __hip_bfloat16* __restrict__ vt,
                                                   const float* __restrict__ qnw,
                                                   const float* __restrict__ cosT,
                                                   const float* __restrict__ sinT,
                                                   const int* __restrict__ pids,
                                                   __hip_bfloat16* __restrict__ ao) {
    __shared__ __align__(16) __hip_bfloat16 Ksl[2][64*D_];    // 2 x 16KB
    __shared__ __align__(16) __hip_bfloat16 Vsl[2][D_*64];    // 2 x 16KB
    const int tid = threadIdx.x;
    const int lane = tid & 63, w = tid >> 6;     // 8 waves
    const int lq = lane & 15, lg = lane >> 4;
    const int blk = blockIdx.x;
    const int qt = blk & 15;
    const int bh = blk >> 4;
    const int h = bh & (H_-1), b = bh >> 5;
    const int g = h >> 2;
    const int q0 = qt*128 + w*16;
    const int q  = q0 + lq;

    const __hip_bfloat16* kbase = kr + ((size_t)b*KVH_ + g) * (size_t)S_ * D_;
    const __hip_bfloat16* vbase = vt + ((size_t)b*KVH_ + g) * (size_t)D_ * S_;

    const int srK = lane >> 4, scK = lane & 15;
    const int srV = lane >> 3, scV = lane & 7;

#define STAGE(nb, k0s) do {                                                              \
    _Pragma("unroll")                                                                    \
    for (int s_ = 0; s_ < 2; ++s_) {                                                     \
        const int rK_ = w*8 + s_*4 + srK;                                                \
        const __hip_bfloat16* srcK_ = kbase + (size_t)((k0s) + rK_)*D_                   \
                                      + ((scK ^ sigk_(rK_)) * 8);                        \
        __builtin_amdgcn_global_load_lds((const GAS void*)srcK_,                         \
            (LAS void*)&Ksl[nb][(w*8 + s_*4)*D_], 16, 0, 0);                             \
    }                                                                                    \
    _Pragma("unroll")                                                                    \
    for (int s_ = 0; s_ < 2; ++s_) {                                                     \
        const int dV_ = w*16 + s_*8 + srV;                                               \
        const __hip_bfloat16* srcV_ = vbase + (size_t)dV_*S_ + (k0s)                     \
                                      + ((scV ^ (dV_ & 7)) * 8);                         \
        __builtin_amdgcn_global_load_lds((const GAS void*)srcV_,                         \
            (LAS void*)&Vsl[nb][(w*16 + s_*8)*64], 16, 0, 0);                            \
    }                                                                                    \
} while (0)

    int kst = qt*128 - (WIN_ - 1); if (kst < 0) kst = 0; kst &= ~63;
    const int nt = qt*2 + 2 - (kst >> 6);

    union { bf16x8 v; __hip_bfloat16 e[8]; } qraw[4];
    const __hip_bfloat16* qb2 = qfb + ((size_t)(b*S_ + q)) * HID_ + h*D_;
    #pragma unroll
    for (int kk = 0; kk < 4; ++kk)
        qraw[kk].v = *(const bf16x8*)(qb2 + kk*32 + lg*8);
    const int p = pids[b*S_ + q];

    STAGE(0, kst);

    float sum = 0.f;
    #pragma unroll
    for (int kk = 0; kk < 4; ++kk)
        #pragma unroll
        for (int j = 0; j < 8; ++j) sum += __bfloat162float(qraw[kk].e[j]);
    sum += __shfl_xor(sum, 16); sum += __shfl_xor(sum, 32);
    const float mu = sum * (1.f / D_);
    float vsq = 0.f;
    #pragma unroll
    for (int kk = 0; kk < 4; ++kk)
        #pragma unroll
        for (int j = 0; j < 8; ++j) {
            const float dxx = __bfloat162float(qraw[kk].e[j]) - mu;
            vsq += dxx * dxx;
        }
    vsq += __shfl_xor(vsq, 16); vsq += __shfl_xor(vsq, 32);
    const float rsq = rsqrtf(vsq * (1.f / D_) + 1e-5f);

    bf16x8 qf[4];
    #pragma unroll
    for (int kk = 0; kk < 4; ++kk) {
        const int d0 = kk*32 + lg*8;
        float wl[8], cc[8], ss[8], y[8];
        *(float4*)&wl[0] = *(const float4*)(qnw + d0);
        *(float4*)&wl[4] = *(const float4*)(qnw + d0 + 4);
        *(float4*)&cc[0] = *(const float4*)(cosT + (size_t)p*D_ + d0);
        *(float4*)&cc[4] = *(const float4*)(cosT + (size_t)p*D_ + d0 + 4);
        *(float4*)&ss[0] = *(const float4*)(sinT + (size_t)p*D_ + d0);
        *(float4*)&ss[4] = *(const float4*)(sinT + (size_t)p*D_ + d0 + 4);
        #pragma unroll
        for (int j = 0; j < 8; ++j)
            y[j] = wl[j] * (__bfloat162float(qraw[kk].e[j]) - mu) * rsq;
        union { bf16x8 v; __hip_bfloat16 e[8]; } qo;
        #pragma unroll
        for (int mpair = 0; mpair < 4; ++mpair) {
            qo.e[2*mpair]   = __float2bfloat16(y[2*mpair]   * cc[2*mpair]   - y[2*mpair+1] * ss[2*mpair]);
            qo.e[2*mpair+1] = __float2bfloat16(y[2*mpair+1] * cc[2*mpair+1] + y[2*mpair]   * ss[2*mpair+1]);
        }
        qf[kk] = qo.v;
    }

    f32x4 o[8] = {};
    float m = -1e30f, l = 0.f;
    const int kldrow = 8*(lq >> 2) + (lq & 3);

    for (int t = 0; t < nt; ++t) {
        const int k0 = kst + t*64;
        const int buf = t & 1;
        if (t + 1 < nt) {
            STAGE((t + 1) & 1, k0 + 64);
            asm volatile("s_waitcnt vmcnt(4)" ::: "memory");
        } else {
            asm volatile("s_waitcnt vmcnt(0)" ::: "memory");
        }
        __builtin_amdgcn_s_barrier();

        f32x4 sc[2][2] = {};
        __builtin_amdgcn_s_setprio(1);
        #pragma unroll
        for (int kb = 0; kb < 2; ++kb)
            #pragma unroll
            for (int f = 0; f < 2; ++f) {
                const int rA = kb*32 + 4*f + kldrow;
                const __hip_bfloat16* kp = &Ksl[buf][rA*D_];
                #pragma unroll
                for (int kk = 0; kk < 4; ++kk) {
                    bf16x8 ka = *(const bf16x8*)(kp + (((kk*4 + lg) ^ sigk_(rA)) * 8));
                    sc[kb][f] = __builtin_amdgcn_mfma_f32_16x16x32_bf16(ka, qf[kk], sc[kb][f], 0, 0, 0);
                }
            }
        __builtin_amdgcn_s_setprio(0);

        const int dqk = q - (k0 + 8*lg);
        float pv[16];
        float mx = -INFINITY;
        #pragma unroll
        for (int kb = 0; kb < 2; ++kb)
            #pragma unroll
            for (int f = 0; f < 2; ++f)
                #pragma unroll
                for (int r = 0; r < 4; ++r) {
                    const int c = kb*32 + 4*f + r;
                    const int d = dqk - c;
                    float v = (d >= 0 && d < WIN_) ? sc[kb][f][r] * SL2E_ : -INFINITY;
                    pv[kb*8 + f*4 + r] = v;
                    mx = fmaxf(mx, v);
                }
        mx = fmaxf(mx, __shfl_xor(mx, 16));
        mx = fmaxf(mx, __shfl_xor(mx, 32));
        const float mn = fmaxf(m, mx);
        const float alpha = exp2f(m - mn);
        float ls = 0.f;
        union { bf16x8 v; __hip_bfloat16 e[8]; } pu[2];
        #pragma unroll
        for (int kb = 0; kb < 2; ++kb)
            #pragma unroll
            for (int j = 0; j < 8; ++j) {
                const float pw = exp2f(pv[kb*8 + j] - mn);
                ls += pw;
                pu[kb].e[j] = __float2bfloat16(pw);
            }
        ls += __shfl_xor(ls, 16);
        ls += __shfl_xor(ls, 32);
        l = l * alpha + ls;
        m = mn;
        #pragma unroll
        for (int n = 0; n < 8; ++n) {
            o[n][0] *= alpha; o[n][1] *= alpha; o[n][2] *= alpha; o[n][3] *= alpha;
        }

        __builtin_amdgcn_s_setprio(1);
        #pragma unroll
        for (int kb = 0; kb < 2; ++kb)
            #pragma unroll
            for (int n = 0; n < 8; ++n) {
                const int dR = n*16 + lq;
                bf16x8 vf8 = *(const bf16x8*)(&Vsl[buf][dR*64] + (((kb*4 + lg) ^ (dR & 7)) * 8));
                o[n] = __builtin_amdgcn_mfma_f32_16x16x32_bf16(vf8, pu[kb].v, o[n], 0, 0, 0);
            }
        __builtin_amdgcn_s_setprio(0);

        if (t + 1 < nt) __builtin_amdgcn_s_barrier();
    }
#undef STAGE

    const float rinv = 1.f / l;
    #pragma unroll
    for (int n = 0; n < 8; ++n) {
        union { bf16x4 v; __hip_bfloat16 e[4]; } ov;
        #pragma unroll
        for (int r = 0; r < 4; ++r) ov.e[r] = __float2bfloat16(o[n][r] * rinv);
        *(bf16x4*)(ao + ((size_t)b*S_ + q)*(H_*D_) + h*D_ + n*16 + lg*4) = ov.v;
    }
}

// ----------------------------------------------------------------- host
extern "C" void kernel_launch(void* const* d_in, const int* in_sizes, int n_in,
                              void* d_out, int out_size, void* d_ws, size_t ws_size,
                              hipStream_t stream) {
    const float* hidden = (const float*)d_in[0];
    const int*   pids   = (const int*)  d_in[1];
    const float* cosT   = (const float*)d_in[2];
    const float* sinT   = (const float*)d_in[3];
    const float* wq     = (const float*)d_in[4];
    const float* wk     = (const float*)d_in[5];
    const float* wv     = (const float*)d_in[6];
    const float* wo     = (const float*)d_in[7];
    const float* qnw    = (const float*)d_in[8];
    const float* knw    = (const float*)d_in[9];
    float* out = (float*)d_out;

    char* base = (char*)d_ws;
    size_t off = 0;
    auto take = [&](size_t bytes) -> void* {
        void* q = base + off;
        off = (off + bytes + 255) & ~(size_t)255;
        return q;
    };
    __hip_bfloat16* qfb  = (__hip_bfloat16*)take((size_t)NROW_*HID_*2);   // Q proj bf16
    __hip_bfloat16* ao   = (__hip_bfloat16*)take((size_t)NROW_*HID_*2);   // attn out bf16
    __hip_bfloat16* hb   = (__hip_bfloat16*)take((size_t)NROW_*HID_*2);
    __hip_bfloat16* wqT  = (__hip_bfloat16*)take((size_t)HID_*HID_*2);
    __hip_bfloat16* wkvT = (__hip_bfloat16*)take((size_t)NKV_*HID_*2);
    __hip_bfloat16* woT  = (__hip_bfloat16*)take((size_t)HID_*HID_*2);
    __hip_bfloat16* kr   = (__hip_bfloat16*)take((size_t)B_*KVH_*S_*D_*2);
    __hip_bfloat16* vt   = (__hip_bfloat16*)take((size_t)B_*KVH_*S_*D_*2);

    if (off > ws_size) {
        fprintf(stderr, "WORKSPACE TOO SMALL: need %zu have %zu\n", off, ws_size);
        return;
    }

    // 1. merged prep: hidden convert + 4 weight transposes (1 launch)
    prep_all<<<16384 + 40960, 256, 0, stream>>>(hidden, wq, wk, wv, wo, hb, wqT, wkvT, woT);

    // 2. projections — every grid exactly 256 blocks (1 round on 256 CUs).
    //    KV GEMM fuses K LayerNorm+RoPE (writes kr) and V transpose (writes vt) in-epilogue.
    gemm_t<4,1><<<(NROW_/256)*(HID_/256), 512, 0, stream>>>(hb, wqT, qfb, nullptr,
        nullptr, nullptr, nullptr, nullptr, NROW_, HID_, HID_, HID_/256);
    gemm_t<2,2><<<(NROW_/256)*(NKV_/128), 512, 0, stream>>>(hb, wkvT, kr, vt,
        knw, cosT, sinT, pids, NROW_, NKV_, HID_, NKV_/128);

    // 3. attention (8 waves, 128 q-rows/block, fused Q LN+RoPE)
    attn_fwd<<<B_*H_*(S_/128), 512, 0, stream>>>(qfb, kr, vt, qnw, cosT, sinT, pids, ao);

    // 4. output projection -> d_out (f32)
    gemm_t<4,0><<<(NROW_/256)*(HID_/256), 512, 0, stream>>>(ao, woT, out, nullptr,
        nullptr, nullptr, nullptr, nullptr, NROW_, HID_, H_*D_, HID_/256);
}